// Round 12
// baseline (2184.053 us; speedup 1.0000x reference)
//
#include <hip/hip_runtime.h>
#include <stdint.h>

typedef int v4i  __attribute__((ext_vector_type(4)));
typedef int v16i __attribute__((ext_vector_type(16)));

// ---------------------------------------------------------------------------
// Kernel 1: quantize activations fp32 -> int8, plus per-row sums.
// ---------------------------------------------------------------------------
__global__ void quant_x_kernel(const float* __restrict__ x,
                               int8_t* __restrict__ xq,
                               int* __restrict__ sum_x,
                               const float* __restrict__ p_scale,
                               const int* __restrict__ p_zp,
                               int K) {
    const int row = blockIdx.x;
    const int t = threadIdx.x;
    const float s = p_scale[0];
    const float zpf = (float)p_zp[0];
    const float* xr = x + (size_t)row * K;
    int8_t* qr = xq + (size_t)row * K;
    int lsum = 0;
    const int nchunk = K >> 10;
    for (int i = 0; i < nchunk; ++i) {
        const int idx = (i << 10) + (t << 2);
        const float4 v = *reinterpret_cast<const float4*>(xr + idx);
        const float f0 = fminf(fmaxf(rintf(v.x / s) + zpf, -128.f), 127.f);
        const float f1 = fminf(fmaxf(rintf(v.y / s) + zpf, -128.f), 127.f);
        const float f2 = fminf(fmaxf(rintf(v.z / s) + zpf, -128.f), 127.f);
        const float f3 = fminf(fmaxf(rintf(v.w / s) + zpf, -128.f), 127.f);
        const int i0 = (int)f0, i1 = (int)f1, i2 = (int)f2, i3 = (int)f3;
        lsum += i0 + i1 + i2 + i3;
        const unsigned pk = (unsigned)(i0 & 255) | ((unsigned)(i1 & 255) << 8) |
                            ((unsigned)(i2 & 255) << 16) | ((unsigned)(i3 & 255) << 24);
        *reinterpret_cast<unsigned*>(qr + idx) = pk;
    }
    __shared__ int wsum[4];
    #pragma unroll
    for (int off = 32; off > 0; off >>= 1) lsum += __shfl_down(lsum, off);
    if ((t & 63) == 0) wsum[t >> 6] = lsum;
    __syncthreads();
    if (t == 0) sum_x[row] = wsum[0] + wsum[1] + wsum[2] + wsum[3];
}

// ---------------------------------------------------------------------------
// Kernel 2: pack weight int32 (int8-valued) -> int8, plus per-row sums.
// ---------------------------------------------------------------------------
__global__ void quant_w_kernel(const int* __restrict__ w,
                               int8_t* __restrict__ wq,
                               int* __restrict__ sum_w,
                               int K) {
    const int row = blockIdx.x;
    const int t = threadIdx.x;
    const int* wr_ = w + (size_t)row * K;
    int8_t* qr = wq + (size_t)row * K;
    int lsum = 0;
    const int nchunk = K >> 10;
    for (int i = 0; i < nchunk; ++i) {
        const int idx = (i << 10) + (t << 2);
        const int4 v = *reinterpret_cast<const int4*>(wr_ + idx);
        lsum += v.x + v.y + v.z + v.w;
        const unsigned pk = (unsigned)(v.x & 255) | ((unsigned)(v.y & 255) << 8) |
                            ((unsigned)(v.z & 255) << 16) | ((unsigned)(v.w & 255) << 24);
        *reinterpret_cast<unsigned*>(qr + idx) = pk;
    }
    __shared__ int wsum[4];
    #pragma unroll
    for (int off = 32; off > 0; off >>= 1) lsum += __shfl_down(lsum, off);
    if ((t & 63) == 0) wsum[t >> 6] = lsum;
    __syncthreads();
    if (t == 0) sum_w[row] = wsum[0] + wsum[1] + wsum[2] + wsum[3];
}

// ---------------------------------------------------------------------------
// Kernel 3: int8 GEMM == r6 skeleton (verified pass) with 2-BLOCKS-PER-CU:
// NSLOT 4->2 (LDS 64 KiB/block), prefetch distance 2->1, tile-end wait
// vmcnt(0), launch_bounds(512,4) -> 16 waves/CU.
//
// Why (r11 post-mortem): every barrier-lockstep schedule serializes the
// LDS-read segment with the MFMA segment (all waves read, barrier, all
// waves MFMA) -> i8 ceiling ~45% (MFMA 1170 + LDS ~1100 + sync per tile);
// measured 28.3 cyc/MFMA constant across r4/r6/r10/r11. Two co-resident
// blocks have INDEPENDENT barriers: block A's read/barrier segment overlaps
// block B's MFMA segment via the CU scheduler (m114: co-scheduled waves,
// time ~ max not sum).
//
// Slot safety (2 slots, distance 1): tile t reads slot t&1; staging writes
// slot (t+1)&1 (disjoint). Staging issues after tile-t start barrier (last
// read of that slot was tile t-1); reads of it occur after tile-end
// vmcnt(0) + barrier. Strictly simpler than r6's distance-2 proof.
//
// Swizzle (r6, verified): stored chunk' = chunk ^ f(row),
// f(row)=((row>>1)^(row>>3))&3; linear DMA dest + inverse-swizzled source.
// XCD swizzle (bijective, nwg=512): v=(bid&7)*64+(bid>>3), y-fastest.
// ---------------------------------------------------------------------------
#define BM 256
#define BN 256
#define BKB 64
#define NSLOT 2

__device__ __forceinline__ void gload_lds16(const void* g, void* l) {
    __builtin_amdgcn_global_load_lds(
        (const __attribute__((address_space(1))) unsigned int*)g,
        (__attribute__((address_space(3))) unsigned int*)l, 16, 0, 0);
}

#define MFMA_I8 __builtin_amdgcn_mfma_i32_32x32x32_i8

__global__ __launch_bounds__(512, 4)
void gemm_i8_kernel(const int8_t* __restrict__ xq,
                    const int8_t* __restrict__ wq,
                    const int* __restrict__ sum_x,
                    const int* __restrict__ sum_w,
                    const float* __restrict__ bias,
                    float* __restrict__ out,
                    const float* __restrict__ p_sa,
                    const int* __restrict__ p_zpa,
                    const float* __restrict__ p_sw,
                    const int* __restrict__ p_wzp,
                    int M, int N, int K) {
    __shared__ v4i ldsA[NSLOT][1024];   // 2 slots * 16KB = 32 KiB
    __shared__ v4i ldsB[NSLOT][1024];   // 64 KiB total -> 2 blocks/CU

    const int tid = threadIdx.x;
    const int lane = tid & 63;
    const int wid = tid >> 6;
    const int wr = wid >> 2;            // 0..1: rows wr*128..+127
    const int wc = wid & 3;             // 0..3: cols wc*64..+63

    // XCD-aware bijective swizzle (nwg = 512, %8 == 0)
    const int nwgy = M / BM;
    const int nwg = nwgy * (N / BN);
    const int bid = blockIdx.x;
    const int v = (bid & 7) * (nwg >> 3) + (bid >> 3);
    const int m0 = (v % nwgy) * BM;
    const int n0 = (v / nwgy) * BN;

    // ---- staging: thread tid fills LDS chunk p = i*512 + tid.
    // row = i*128 + (tid>>2), stored chunk' = tid&3; source logical chunk =
    // chunk' ^ f(row), f(row) = ((row>>1)^(row>>3))&3.
    const int srow = tid >> 2;                          // 0..127
    const int schunk = (tid & 3) ^ (((srow >> 1) ^ (srow >> 3)) & 3);
    const int8_t* aS = xq + (size_t)(m0 + srow) * K + schunk * 16;
    const int8_t* bS = wq + (size_t)(n0 + srow) * K + schunk * 16;
    const size_t half = (size_t)128 * K;                // +128 rows
    const int dbase = wid * 64;                         // wave-uniform

    // ---- fragment reads (swizzled as stored)
    const int sel = ((lane >> 1) ^ (lane >> 3)) & 3;
    const int hi = lane >> 5;
    const int abase = (wr * 128 + (lane & 31)) * 4;
    const int bbase = (wc * 64 + (lane & 31)) * 4;
    const int c00 = hi ^ sel;          // ks0 stored chunk
    const int c01 = (2 + hi) ^ sel;    // ks1 stored chunk

    v16i acc[4][2] = {};
    const int NT = K / BKB;

    // ---- prologue: stage tile 0 into slot 0
    gload_lds16(aS,        &ldsA[0][dbase]);
    gload_lds16(aS + half, &ldsA[0][dbase + 512]);
    gload_lds16(bS,        &ldsB[0][dbase]);
    gload_lds16(bS + half, &ldsB[0][dbase + 512]);
    asm volatile("s_waitcnt vmcnt(0)" ::: "memory");
    __builtin_amdgcn_sched_barrier(0);
    __builtin_amdgcn_s_barrier();

    for (int t = 0; t < NT; ++t) {
        const v4i* LA = ldsA[t & 1];
        const v4i* LB = ldsB[t & 1];

        // ========== phase 0: B(all) + A rf0,rf1 reads; stage A(t+1) ========
        const v4i b00 = LB[bbase + c00];
        const v4i b01 = LB[bbase + c01];
        const v4i b10 = LB[bbase + 128 + c00];
        const v4i b11 = LB[bbase + 128 + c01];
        const v4i a00 = LA[abase + c00];
        const v4i a01 = LA[abase + c01];
        const v4i a10 = LA[abase + 128 + c00];
        const v4i a11 = LA[abase + 128 + c01];
        if (t + 1 < NT) {
            const int ns = (t + 1) & 1;
            const int8_t* p = aS + (size_t)(t + 1) * BKB;
            gload_lds16(p,        &ldsA[ns][dbase]);
            gload_lds16(p + half, &ldsA[ns][dbase + 512]);
        }
        __builtin_amdgcn_s_barrier();
        __builtin_amdgcn_s_setprio(1);
        acc[0][0] = MFMA_I8(a00, b00, acc[0][0], 0, 0, 0);
        acc[0][1] = MFMA_I8(a00, b10, acc[0][1], 0, 0, 0);
        acc[1][0] = MFMA_I8(a10, b00, acc[1][0], 0, 0, 0);
        acc[1][1] = MFMA_I8(a10, b10, acc[1][1], 0, 0, 0);
        acc[0][0] = MFMA_I8(a01, b01, acc[0][0], 0, 0, 0);
        acc[0][1] = MFMA_I8(a01, b11, acc[0][1], 0, 0, 0);
        acc[1][0] = MFMA_I8(a11, b01, acc[1][0], 0, 0, 0);
        acc[1][1] = MFMA_I8(a11, b11, acc[1][1], 0, 0, 0);
        __builtin_amdgcn_s_setprio(0);
        __builtin_amdgcn_s_barrier();

        // ========== phase 1: A rf2,rf3 reads; stage B(t+1) =================
        const v4i a20 = LA[abase + 256 + c00];
        const v4i a21 = LA[abase + 256 + c01];
        const v4i a30 = LA[abase + 384 + c00];
        const v4i a31 = LA[abase + 384 + c01];
        if (t + 1 < NT) {
            const int ns = (t + 1) & 1;
            const int8_t* p = bS + (size_t)(t + 1) * BKB;
            gload_lds16(p,        &ldsB[ns][dbase]);
            gload_lds16(p + half, &ldsB[ns][dbase + 512]);
        }
        __builtin_amdgcn_s_barrier();
        __builtin_amdgcn_s_setprio(1);
        acc[2][0] = MFMA_I8(a20, b00, acc[2][0], 0, 0, 0);
        acc[2][1] = MFMA_I8(a20, b10, acc[2][1], 0, 0, 0);
        acc[3][0] = MFMA_I8(a30, b00, acc[3][0], 0, 0, 0);
        acc[3][1] = MFMA_I8(a30, b10, acc[3][1], 0, 0, 0);
        acc[2][0] = MFMA_I8(a21, b01, acc[2][0], 0, 0, 0);
        acc[2][1] = MFMA_I8(a21, b11, acc[2][1], 0, 0, 0);
        acc[3][0] = MFMA_I8(a31, b01, acc[3][0], 0, 0, 0);
        acc[3][1] = MFMA_I8(a31, b11, acc[3][1], 0, 0, 0);
        __builtin_amdgcn_s_setprio(0);
        // distance-1: staging of t+1 must be complete before next tile.
        asm volatile("s_waitcnt vmcnt(0)" ::: "memory");
        __builtin_amdgcn_sched_barrier(0);
        __builtin_amdgcn_s_barrier();
    }

    // ---- epilogue: y = (acc - wzp*sum_x[m] - zp*sum_w[n] + K*zp*wzp)*(sa*sw) + bias[n]
    const float stot = p_sa[0] * p_sw[0];
    const int zpa = p_zpa[0];
    const int wzp = p_wzp[0];
    const int kzz = K * zpa * wzp;
    const int coll = lane & 31;
    const int rhi = (lane >> 5) * 4;

    #pragma unroll
    for (int cf = 0; cf < 2; ++cf) {
        const int cg = n0 + wc * 64 + cf * 32 + coll;
        const int sw = sum_w[cg];
        const float bb = bias[cg];
        #pragma unroll
        for (int rf = 0; rf < 4; ++rf) {
            const int rbase = m0 + wr * 128 + rf * 32 + rhi;
            #pragma unroll
            for (int r = 0; r < 16; ++r) {
                const int rowg = rbase + (r & 3) + 8 * (r >> 2);
                const int iv = acc[rf][cf][r] - wzp * sum_x[rowg] - zpa * sw + kzz;
                out[(size_t)rowg * N + cg] = (float)iv * stot + bb;
            }
        }
    }
}

// ---------------------------------------------------------------------------
extern "C" void kernel_launch(void* const* d_in, const int* in_sizes, int n_in,
                              void* d_out, int out_size, void* d_ws, size_t ws_size,
                              hipStream_t stream) {
    const float* x     = (const float*)d_in[0];
    const int*   w     = (const int*)d_in[1];
    const float* bias  = (const float*)d_in[2];
    const float* p_sa  = (const float*)d_in[3];
    const int*   p_zpa = (const int*)d_in[4];
    const float* p_sw  = (const float*)d_in[5];
    const int*   p_wzp = (const int*)d_in[6];

    const int N = in_sizes[2];             // OUT
    const int K = in_sizes[1] / N;         // IN
    const int M = in_sizes[0] / K;         // B*S

    int8_t* xq = (int8_t*)d_ws;
    int8_t* wq = xq + (size_t)M * K;
    int* sum_x = (int*)(wq + (size_t)N * K);
    int* sum_w = sum_x + M;

    quant_x_kernel<<<M, 256, 0, stream>>>(x, xq, sum_x, p_sa, p_zpa, K);
    quant_w_kernel<<<N, 256, 0, stream>>>(w, wq, sum_w, K);

    const int nwg = (M / BM) * (N / BN);   // 512 = 2 per CU
    gemm_i8_kernel<<<nwg, 512, 0, stream>>>(xq, wq, sum_x, sum_w, bias,
                                            (float*)d_out, p_sa, p_zpa, p_sw, p_wzp,
                                            M, N, K);
}

// Round 13
// 394.800 us; speedup vs baseline: 5.5321x; 5.5321x over previous
//
#include <hip/hip_runtime.h>
#include <stdint.h>

typedef int v4i  __attribute__((ext_vector_type(4)));
typedef int v16i __attribute__((ext_vector_type(16)));

// ---------------------------------------------------------------------------
// Kernel 1: quantize activations fp32 -> int8, plus per-row sums.
// ---------------------------------------------------------------------------
__global__ void quant_x_kernel(const float* __restrict__ x,
                               int8_t* __restrict__ xq,
                               int* __restrict__ sum_x,
                               const float* __restrict__ p_scale,
                               const int* __restrict__ p_zp,
                               int K) {
    const int row = blockIdx.x;
    const int t = threadIdx.x;
    const float s = p_scale[0];
    const float zpf = (float)p_zp[0];
    const float* xr = x + (size_t)row * K;
    int8_t* qr = xq + (size_t)row * K;
    int lsum = 0;
    const int nchunk = K >> 10;
    for (int i = 0; i < nchunk; ++i) {
        const int idx = (i << 10) + (t << 2);
        const float4 v = *reinterpret_cast<const float4*>(xr + idx);
        const float f0 = fminf(fmaxf(rintf(v.x / s) + zpf, -128.f), 127.f);
        const float f1 = fminf(fmaxf(rintf(v.y / s) + zpf, -128.f), 127.f);
        const float f2 = fminf(fmaxf(rintf(v.z / s) + zpf, -128.f), 127.f);
        const float f3 = fminf(fmaxf(rintf(v.w / s) + zpf, -128.f), 127.f);
        const int i0 = (int)f0, i1 = (int)f1, i2 = (int)f2, i3 = (int)f3;
        lsum += i0 + i1 + i2 + i3;
        const unsigned pk = (unsigned)(i0 & 255) | ((unsigned)(i1 & 255) << 8) |
                            ((unsigned)(i2 & 255) << 16) | ((unsigned)(i3 & 255) << 24);
        *reinterpret_cast<unsigned*>(qr + idx) = pk;
    }
    __shared__ int wsum[4];
    #pragma unroll
    for (int off = 32; off > 0; off >>= 1) lsum += __shfl_down(lsum, off);
    if ((t & 63) == 0) wsum[t >> 6] = lsum;
    __syncthreads();
    if (t == 0) sum_x[row] = wsum[0] + wsum[1] + wsum[2] + wsum[3];
}

// ---------------------------------------------------------------------------
// Kernel 2: pack weight int32 (int8-valued) -> int8, plus per-row sums.
// ---------------------------------------------------------------------------
__global__ void quant_w_kernel(const int* __restrict__ w,
                               int8_t* __restrict__ wq,
                               int* __restrict__ sum_w,
                               int K) {
    const int row = blockIdx.x;
    const int t = threadIdx.x;
    const int* wr_ = w + (size_t)row * K;
    int8_t* qr = wq + (size_t)row * K;
    int lsum = 0;
    const int nchunk = K >> 10;
    for (int i = 0; i < nchunk; ++i) {
        const int idx = (i << 10) + (t << 2);
        const int4 v = *reinterpret_cast<const int4*>(wr_ + idx);
        lsum += v.x + v.y + v.z + v.w;
        const unsigned pk = (unsigned)(v.x & 255) | ((unsigned)(v.y & 255) << 8) |
                            ((unsigned)(v.z & 255) << 16) | ((unsigned)(v.w & 255) << 24);
        *reinterpret_cast<unsigned*>(qr + idx) = pk;
    }
    __shared__ int wsum[4];
    #pragma unroll
    for (int off = 32; off > 0; off >>= 1) lsum += __shfl_down(lsum, off);
    if ((t & 63) == 0) wsum[t >> 6] = lsum;
    __syncthreads();
    if (t == 0) sum_w[row] = wsum[0] + wsum[1] + wsum[2] + wsum[3];
}

// ---------------------------------------------------------------------------
// Kernel 3: int8 GEMM, 256x256, 8 waves (2x4). A DIRECT global->VGPR
// (double-buffered named reg sets, prefetched one full tile ahead);
// B via the r6-verified DMA staging into a 2-slot LDS (32 KiB only).
//
// Why (r4-r12 consolidated model): every LDS-lockstep variant costs
// ~3600 cyc/tile because the single per-CU LDS port (A+B reads 96KB ~1150cyc
// + DMA writes ~400cyc) serializes against the MFMA pipe (1170cyc); i8's
// fast matrix pipe pins this at ~31% MfmaUtil regardless of phase schedule
// (bf16's 62% in m201 is the same arithmetic with 2x slower MFMA). Fix =
// move A off the LDS port: VMEM/L1/L2 pipe carries A (panel is 1MB,
// L2-resident under XCD swizzle; the ks0/ks1 fragment pair covers each
// row's full 64B line -> clean L2 lines), LDS carries only B
// (reads 32KB ~380cyc + writes 16KB ~150cyc << MFMA). Three independent
// pipes -> ceiling becomes the matrix pipe.
//
// Correctness rules honored:
//  - ALL explicit waits are vmcnt(0) (r9-proven safe for mixed DMA+VGPR
//    streams; counted-N over mixed streams is the r7/r8 race -- excluded).
//  - A(t+1) regs: named sets via 2x-unrolled macro (rule 20), written only
//    after the MFMAs that consume the other set (register WAR).
//  - B slots: stage (t+1)&1 during tile t (disjoint from read slot t&1);
//    overwrite of slot t&1 happens in tile t+1, one barrier after its last
//    read; DMA retired by tile-end vmcnt(0)+barrier before readers. SAFE.
//  - launch_bounds(512,1): no register cap (r12 lesson: min-waves 4 forced
//    a 64-VGPR cap -> acc spilled -> 2129us).
// ---------------------------------------------------------------------------
#define BM 256
#define BN 256
#define BKB 64

__device__ __forceinline__ void gload_lds16(const void* g, void* l) {
    __builtin_amdgcn_global_load_lds(
        (const __attribute__((address_space(1))) unsigned int*)g,
        (__attribute__((address_space(3))) unsigned int*)l, 16, 0, 0);
}

#define MFMA_I8 __builtin_amdgcn_mfma_i32_32x32x32_i8

__global__ __launch_bounds__(512, 1)
void gemm_i8_kernel(const int8_t* __restrict__ xq,
                    const int8_t* __restrict__ wq,
                    const int* __restrict__ sum_x,
                    const int* __restrict__ sum_w,
                    const float* __restrict__ bias,
                    float* __restrict__ out,
                    const float* __restrict__ p_sa,
                    const int* __restrict__ p_zpa,
                    const float* __restrict__ p_sw,
                    const int* __restrict__ p_wzp,
                    int M, int N, int K) {
    __shared__ v4i ldsB[2][1024];       // 2 slots * 16 KiB = 32 KiB (B only)

    const int tid = threadIdx.x;
    const int lane = tid & 63;
    const int wid = tid >> 6;
    const int wr = wid >> 2;            // 0..1: rows wr*128..+127
    const int wc = wid & 3;             // 0..3: cols wc*64..+63

    // XCD-aware bijective swizzle (nwg = 512, %8 == 0)
    const int nwgy = M / BM;
    const int nwg = nwgy * (N / BN);
    const int bid = blockIdx.x;
    const int v = (bid & 7) * (nwg >> 3) + (bid >> 3);
    const int m0 = (v % nwgy) * BM;
    const int n0 = (v / nwgy) * BN;

    // ---- B staging (r6-verified): thread tid fills chunk p = i*512 + tid.
    // row = i*128 + (tid>>2), stored chunk' = tid&3; source logical chunk =
    // chunk' ^ f(row), f(row) = ((row>>1)^(row>>3))&3.
    const int srow = tid >> 2;
    const int schunk = (tid & 3) ^ (((srow >> 1) ^ (srow >> 3)) & 3);
    const int8_t* bS = wq + (size_t)(n0 + srow) * K + schunk * 16;
    const size_t half = (size_t)128 * K;
    const int dbase = wid * 64;

    // ---- B fragment reads (swizzled as stored)
    const int sel = ((lane >> 1) ^ (lane >> 3)) & 3;
    const int hi = lane >> 5;
    const int bbase = (wc * 64 + (lane & 31)) * 4;
    const int c00 = hi ^ sel;          // ks0 stored chunk
    const int c01 = (2 + hi) ^ sel;    // ks1 stored chunk

    // ---- A direct-from-global: lane l covers row m0 + wr*128 + rf*32 +
    // (l&31), kbyte t*64 + ks*32 + (l>>5)*16  (the r1-r11 verified layout).
    const int8_t* aP = xq + (size_t)(m0 + wr * 128 + (lane & 31)) * K + ((lane >> 5) << 4);
    const size_t arf = (size_t)32 * K;  // rf stride (32 rows)

    v16i acc[4][2] = {};
    v4i afA[8], afB[8];                 // named A double-buffer [rf*2+ks]

    const int NT = K / BKB;             // 64 (even)

    // ---- prologue: stage B(0); load A(0) into afA; drain; publish.
    gload_lds16(bS,        &ldsB[0][dbase]);
    gload_lds16(bS + half, &ldsB[0][dbase + 512]);
    #pragma unroll
    for (int rf = 0; rf < 4; ++rf) {
        afA[rf * 2 + 0] = *reinterpret_cast<const v4i*>(aP + rf * arf);
        afA[rf * 2 + 1] = *reinterpret_cast<const v4i*>(aP + rf * arf + 32);
    }
    asm volatile("s_waitcnt vmcnt(0)" ::: "memory");
    __builtin_amdgcn_sched_barrier(0);
    __builtin_amdgcn_s_barrier();

    // One K-tile: read B frags (slot t&1), stage B(t+1), prefetch A(t+1)
    // into the alternate reg set, 16 MFMA on current set, drain, barrier.
#define TILE(ACUR, ANXT, T_) do {                                             \
        const int t_ = (T_);                                                  \
        const v4i* LB = ldsB[t_ & 1];                                         \
        const v4i b00 = LB[bbase + c00];                                      \
        const v4i b01 = LB[bbase + c01];                                      \
        const v4i b10 = LB[bbase + 128 + c00];                                \
        const v4i b11 = LB[bbase + 128 + c01];                                \
        if (t_ + 1 < NT) {                                                    \
            const int8_t* pb = bS + (size_t)(t_ + 1) * BKB;                   \
            gload_lds16(pb,        &ldsB[(t_ + 1) & 1][dbase]);               \
            gload_lds16(pb + half, &ldsB[(t_ + 1) & 1][dbase + 512]);         \
            const int8_t* pa = aP + (size_t)(t_ + 1) * BKB;                   \
            _Pragma("unroll")                                                 \
            for (int rf = 0; rf < 4; ++rf) {                                  \
                ANXT[rf * 2 + 0] = *reinterpret_cast<const v4i*>(pa + rf * arf);      \
                ANXT[rf * 2 + 1] = *reinterpret_cast<const v4i*>(pa + rf * arf + 32); \
            }                                                                 \
        }                                                                     \
        __builtin_amdgcn_s_setprio(1);                                        \
        acc[0][0] = MFMA_I8(ACUR[0], b00, acc[0][0], 0, 0, 0);                \
        acc[0][1] = MFMA_I8(ACUR[0], b10, acc[0][1], 0, 0, 0);                \
        acc[1][0] = MFMA_I8(ACUR[2], b00, acc[1][0], 0, 0, 0);                \
        acc[1][1] = MFMA_I8(ACUR[2], b10, acc[1][1], 0, 0, 0);                \
        acc[2][0] = MFMA_I8(ACUR[4], b00, acc[2][0], 0, 0, 0);                \
        acc[2][1] = MFMA_I8(ACUR[4], b10, acc[2][1], 0, 0, 0);                \
        acc[3][0] = MFMA_I8(ACUR[6], b00, acc[3][0], 0, 0, 0);                \
        acc[3][1] = MFMA_I8(ACUR[6], b10, acc[3][1], 0, 0, 0);                \
        acc[0][0] = MFMA_I8(ACUR[1], b01, acc[0][0], 0, 0, 0);                \
        acc[0][1] = MFMA_I8(ACUR[1], b11, acc[0][1], 0, 0, 0);                \
        acc[1][0] = MFMA_I8(ACUR[3], b01, acc[1][0], 0, 0, 0);                \
        acc[1][1] = MFMA_I8(ACUR[3], b11, acc[1][1], 0, 0, 0);                \
        acc[2][0] = MFMA_I8(ACUR[5], b01, acc[2][0], 0, 0, 0);                \
        acc[2][1] = MFMA_I8(ACUR[5], b11, acc[2][1], 0, 0, 0);                \
        acc[3][0] = MFMA_I8(ACUR[7], b01, acc[3][0], 0, 0, 0);                \
        acc[3][1] = MFMA_I8(ACUR[7], b11, acc[3][1], 0, 0, 0);                \
        __builtin_amdgcn_s_setprio(0);                                        \
        asm volatile("s_waitcnt vmcnt(0)" ::: "memory");                      \
        __builtin_amdgcn_sched_barrier(0);                                    \
        __builtin_amdgcn_s_barrier();                                         \
    } while (0)

    for (int tt = 0; tt < NT; tt += 2) {
        TILE(afA, afB, tt);
        TILE(afB, afA, tt + 1);
    }
#undef TILE

    // ---- epilogue: y = (acc - wzp*sum_x[m] - zp*sum_w[n] + K*zp*wzp)*(sa*sw) + bias[n]
    const float stot = p_sa[0] * p_sw[0];
    const int zpa = p_zpa[0];
    const int wzp = p_wzp[0];
    const int kzz = K * zpa * wzp;
    const int coll = lane & 31;
    const int rhi = (lane >> 5) * 4;

    #pragma unroll
    for (int cf = 0; cf < 2; ++cf) {
        const int cg = n0 + wc * 64 + cf * 32 + coll;
        const int sw = sum_w[cg];
        const float bb = bias[cg];
        #pragma unroll
        for (int rf = 0; rf < 4; ++rf) {
            const int rbase = m0 + wr * 128 + rf * 32 + rhi;
            #pragma unroll
            for (int r = 0; r < 16; ++r) {
                const int rowg = rbase + (r & 3) + 8 * (r >> 2);
                const int iv = acc[rf][cf][r] - wzp * sum_x[rowg] - zpa * sw + kzz;
                out[(size_t)rowg * N + cg] = (float)iv * stot + bb;
            }
        }
    }
}

// ---------------------------------------------------------------------------
extern "C" void kernel_launch(void* const* d_in, const int* in_sizes, int n_in,
                              void* d_out, int out_size, void* d_ws, size_t ws_size,
                              hipStream_t stream) {
    const float* x     = (const float*)d_in[0];
    const int*   w     = (const int*)d_in[1];
    const float* bias  = (const float*)d_in[2];
    const float* p_sa  = (const float*)d_in[3];
    const int*   p_zpa = (const int*)d_in[4];
    const float* p_sw  = (const float*)d_in[5];
    const int*   p_wzp = (const int*)d_in[6];

    const int N = in_sizes[2];             // OUT
    const int K = in_sizes[1] / N;         // IN
    const int M = in_sizes[0] / K;         // B*S

    int8_t* xq = (int8_t*)d_ws;
    int8_t* wq = xq + (size_t)M * K;
    int* sum_x = (int*)(wq + (size_t)N * K);
    int* sum_w = sum_x + M;

    quant_x_kernel<<<M, 256, 0, stream>>>(x, xq, sum_x, p_sa, p_zpa, K);
    quant_w_kernel<<<N, 256, 0, stream>>>(w, wq, sum_w, K);

    const int nwg = (M / BM) * (N / BN);   // 512
    gemm_i8_kernel<<<nwg, 512, 0, stream>>>(xq, wq, sum_x, sum_w, bias,
                                            (float*)d_out, p_sa, p_zpa, p_sw, p_wzp,
                                            M, N, K);
}

// Round 14
// 248.035 us; speedup vs baseline: 8.8054x; 1.5917x over previous
//
#include <hip/hip_runtime.h>
#include <stdint.h>

typedef int v4i  __attribute__((ext_vector_type(4)));
typedef int v16i __attribute__((ext_vector_type(16)));

// ---------------------------------------------------------------------------
// Kernel 1: quantize activations fp32 -> int8, plus per-row sums.
// ---------------------------------------------------------------------------
__global__ void quant_x_kernel(const float* __restrict__ x,
                               int8_t* __restrict__ xq,
                               int* __restrict__ sum_x,
                               const float* __restrict__ p_scale,
                               const int* __restrict__ p_zp,
                               int K) {
    const int row = blockIdx.x;
    const int t = threadIdx.x;
    const float s = p_scale[0];
    const float zpf = (float)p_zp[0];
    const float* xr = x + (size_t)row * K;
    int8_t* qr = xq + (size_t)row * K;
    int lsum = 0;
    const int nchunk = K >> 10;
    for (int i = 0; i < nchunk; ++i) {
        const int idx = (i << 10) + (t << 2);
        const float4 v = *reinterpret_cast<const float4*>(xr + idx);
        const float f0 = fminf(fmaxf(rintf(v.x / s) + zpf, -128.f), 127.f);
        const float f1 = fminf(fmaxf(rintf(v.y / s) + zpf, -128.f), 127.f);
        const float f2 = fminf(fmaxf(rintf(v.z / s) + zpf, -128.f), 127.f);
        const float f3 = fminf(fmaxf(rintf(v.w / s) + zpf, -128.f), 127.f);
        const int i0 = (int)f0, i1 = (int)f1, i2 = (int)f2, i3 = (int)f3;
        lsum += i0 + i1 + i2 + i3;
        const unsigned pk = (unsigned)(i0 & 255) | ((unsigned)(i1 & 255) << 8) |
                            ((unsigned)(i2 & 255) << 16) | ((unsigned)(i3 & 255) << 24);
        *reinterpret_cast<unsigned*>(qr + idx) = pk;
    }
    __shared__ int wsum[4];
    #pragma unroll
    for (int off = 32; off > 0; off >>= 1) lsum += __shfl_down(lsum, off);
    if ((t & 63) == 0) wsum[t >> 6] = lsum;
    __syncthreads();
    if (t == 0) sum_x[row] = wsum[0] + wsum[1] + wsum[2] + wsum[3];
}

// ---------------------------------------------------------------------------
// Kernel 2: pack weight int32 (int8-valued) -> int8, plus per-row sums.
// ---------------------------------------------------------------------------
__global__ void quant_w_kernel(const int* __restrict__ w,
                               int8_t* __restrict__ wq,
                               int* __restrict__ sum_w,
                               int K) {
    const int row = blockIdx.x;
    const int t = threadIdx.x;
    const int* wr_ = w + (size_t)row * K;
    int8_t* qr = wq + (size_t)row * K;
    int lsum = 0;
    const int nchunk = K >> 10;
    for (int i = 0; i < nchunk; ++i) {
        const int idx = (i << 10) + (t << 2);
        const int4 v = *reinterpret_cast<const int4*>(wr_ + idx);
        lsum += v.x + v.y + v.z + v.w;
        const unsigned pk = (unsigned)(v.x & 255) | ((unsigned)(v.y & 255) << 8) |
                            ((unsigned)(v.z & 255) << 16) | ((unsigned)(v.w & 255) << 24);
        *reinterpret_cast<unsigned*>(qr + idx) = pk;
    }
    __shared__ int wsum[4];
    #pragma unroll
    for (int off = 32; off > 0; off >>= 1) lsum += __shfl_down(lsum, off);
    if ((t & 63) == 0) wsum[t >> 6] = lsum;
    __syncthreads();
    if (t == 0) sum_w[row] = wsum[0] + wsum[1] + wsum[2] + wsum[3];
}

// ---------------------------------------------------------------------------
// Kernel 3: int8 GEMM, 256x128 block tile, 8 waves (4x2), wave-tile 64x64,
// TWO BLOCKS CO-RESIDENT PER CU (the r4-r13 consolidated fix).
//
// Model: all single-block lockstep structures cost ~3600 cyc/tile because
// MFMA (1170) and LDS-port traffic (~1500) SERIALIZE -- no independent
// instruction stream exists to overlap them. m114: the CU scheduler fully
// overlaps independent waves (time ~ max, not sum). Two co-resident blocks
// have independent barriers -> block A's read/stage segment overlaps block
// B's MFMA segment.
//
// Register budget (the r12 lesson -- 2 blocks/CU needs <= 128 regs/wave,
// m69): acc 64 (v16i x 2x2) + frags 32 + addresses ~24 = ~120 <= 128.
// __launch_bounds__(512,4) = 4 waves/EU = 2 blocks/CU.
// CHECK IN COUNTERS: VGPR_Count <= 128 and FETCH ~200MB (no spill); spill
// would show VGPR 64 / FETCH in GB (r12 signature).
//
// LDS: 2 slots x (A 16KB + B 8KB) = 48 KB/block, 96 KB/CU.
// Skeleton: r10/r12-verified single-phase tile -- read 8 frags (slot t&1),
// stage tile t+1 into slot (t+1)&1 (3 pure-DMA gload_lds calls), 8 MFMA,
// vmcnt(0) [r9-verified safe], sched_barrier, s_barrier. Slot WAR: staging
// targets the slot NOT being read; overwrite of a read slot happens one
// barrier after its reads were consumed (lgkmcnt before MFMA before
// barrier). Pure-DMA + vmcnt(0): no counted-N over mixed streams.
//
// Swizzle (r6-verified): stored chunk' = chunk ^ f(row),
// f(row)=((row>>1)^(row>>3))&3; linear DMA dest, inverse-swizzled source.
// XCD swizzle (bijective, nwg=1024 %8==0): v=(bid&7)*(nwg/8)+(bid>>3).
// ---------------------------------------------------------------------------
#define BM 256
#define BN 128
#define BKB 64

__device__ __forceinline__ void gload_lds16(const void* g, void* l) {
    __builtin_amdgcn_global_load_lds(
        (const __attribute__((address_space(1))) unsigned int*)g,
        (__attribute__((address_space(3))) unsigned int*)l, 16, 0, 0);
}

#define MFMA_I8 __builtin_amdgcn_mfma_i32_32x32x32_i8

__global__ __launch_bounds__(512, 4)
void gemm_i8_kernel(const int8_t* __restrict__ xq,
                    const int8_t* __restrict__ wq,
                    const int* __restrict__ sum_x,
                    const int* __restrict__ sum_w,
                    const float* __restrict__ bias,
                    float* __restrict__ out,
                    const float* __restrict__ p_sa,
                    const int* __restrict__ p_zpa,
                    const float* __restrict__ p_sw,
                    const int* __restrict__ p_wzp,
                    int M, int N, int K) {
    __shared__ v4i ldsA[2][1024];       // 2 slots * 16 KiB
    __shared__ v4i ldsB[2][512];        // 2 slots *  8 KiB  (48 KiB total)

    const int tid = threadIdx.x;
    const int lane = tid & 63;
    const int wid = tid >> 6;
    const int wr = wid >> 1;            // 0..3: rows wr*64..+63
    const int wc = wid & 1;             // 0..1: cols wc*64..+63

    // XCD-aware bijective swizzle (nwg = 32*32 = 1024, %8 == 0)
    const int nwgy = M / BM;            // 32
    const int nwg = nwgy * (N / BN);    // 1024
    const int bid = blockIdx.x;
    const int v = (bid & 7) * (nwg >> 3) + (bid >> 3);
    const int m0 = (v % nwgy) * BM;
    const int n0 = (v / nwgy) * BN;

    // ---- staging (r6 pattern): thread tid fills LDS chunk p = i*512 + tid.
    // row = i*128 + (tid>>2), stored chunk' = tid&3; source logical chunk =
    // chunk' ^ f(row), f(row) = ((row>>1)^(row>>3))&3.
    const int srow = tid >> 2;                          // 0..127
    const int schunk = (tid & 3) ^ (((srow >> 1) ^ (srow >> 3)) & 3);
    const int8_t* aS = xq + (size_t)(m0 + srow) * K + schunk * 16;
    const int8_t* bS = wq + (size_t)(n0 + srow) * K + schunk * 16;
    const size_t half = (size_t)128 * K;                // A rows 128..255
    const int dbase = wid * 64;                         // wave-uniform

    // ---- fragment reads (swizzled as stored); frag row base % 32 == 0.
    const int sel = ((lane >> 1) ^ (lane >> 3)) & 3;
    const int hi = lane >> 5;
    const int aU = (wr * 64 + (lane & 31)) * 4;
    const int bU = (wc * 64 + (lane & 31)) * 4;
    const int c0 = hi ^ sel;            // ks0 stored chunk
    const int c1 = (2 + hi) ^ sel;      // ks1 stored chunk

    v16i acc[2][2] = {};
    const int NT = K / BKB;             // 64

    // ---- prologue: stage tile 0 into slot 0; drain; publish.
    gload_lds16(aS,        &ldsA[0][dbase]);
    gload_lds16(aS + half, &ldsA[0][512 + dbase]);
    gload_lds16(bS,        &ldsB[0][dbase]);
    asm volatile("s_waitcnt vmcnt(0)" ::: "memory");
    __builtin_amdgcn_sched_barrier(0);
    __builtin_amdgcn_s_barrier();

    for (int t = 0; t < NT; ++t) {
        const v4i* LA = ldsA[t & 1];
        const v4i* LB = ldsB[t & 1];
        const v4i a00 = LA[aU + c0];
        const v4i a01 = LA[aU + c1];
        const v4i a10 = LA[aU + 128 + c0];
        const v4i a11 = LA[aU + 128 + c1];
        const v4i b00 = LB[bU + c0];
        const v4i b01 = LB[bU + c1];
        const v4i b10 = LB[bU + 128 + c0];
        const v4i b11 = LB[bU + 128 + c1];
        if (t + 1 < NT) {
            const int ns = (t + 1) & 1;
            const int8_t* pa = aS + (size_t)(t + 1) * BKB;
            gload_lds16(pa,        &ldsA[ns][dbase]);
            gload_lds16(pa + half, &ldsA[ns][512 + dbase]);
            gload_lds16(bS + (size_t)(t + 1) * BKB, &ldsB[ns][dbase]);
        }
        __builtin_amdgcn_s_setprio(1);
        acc[0][0] = MFMA_I8(a00, b00, acc[0][0], 0, 0, 0);
        acc[0][1] = MFMA_I8(a00, b10, acc[0][1], 0, 0, 0);
        acc[1][0] = MFMA_I8(a10, b00, acc[1][0], 0, 0, 0);
        acc[1][1] = MFMA_I8(a10, b10, acc[1][1], 0, 0, 0);
        acc[0][0] = MFMA_I8(a01, b01, acc[0][0], 0, 0, 0);
        acc[0][1] = MFMA_I8(a01, b11, acc[0][1], 0, 0, 0);
        acc[1][0] = MFMA_I8(a11, b01, acc[1][0], 0, 0, 0);
        acc[1][1] = MFMA_I8(a11, b11, acc[1][1], 0, 0, 0);
        __builtin_amdgcn_s_setprio(0);
        // distance-1: all of tile t+1's staging must land before next tile.
        asm volatile("s_waitcnt vmcnt(0)" ::: "memory");
        __builtin_amdgcn_sched_barrier(0);
        __builtin_amdgcn_s_barrier();
    }

    // ---- epilogue: y = (acc - wzp*sum_x[m] - zp*sum_w[n] + K*zp*wzp)*(sa*sw) + bias[n]
    const float stot = p_sa[0] * p_sw[0];
    const int zpa = p_zpa[0];
    const int wzp = p_wzp[0];
    const int kzz = K * zpa * wzp;
    const int coll = lane & 31;
    const int rhi = (lane >> 5) * 4;

    #pragma unroll
    for (int cf = 0; cf < 2; ++cf) {
        const int cg = n0 + wc * 64 + cf * 32 + coll;
        const int sw = sum_w[cg];
        const float bb = bias[cg];
        #pragma unroll
        for (int rf = 0; rf < 2; ++rf) {
            const int rbase = m0 + wr * 64 + rf * 32 + rhi;
            #pragma unroll
            for (int r = 0; r < 16; ++r) {
                const int rowg = rbase + (r & 3) + 8 * (r >> 2);
                const int iv = acc[rf][cf][r] - wzp * sum_x[rowg] - zpa * sw + kzz;
                out[(size_t)rowg * N + cg] = (float)iv * stot + bb;
            }
        }
    }
}

// ---------------------------------------------------------------------------
extern "C" void kernel_launch(void* const* d_in, const int* in_sizes, int n_in,
                              void* d_out, int out_size, void* d_ws, size_t ws_size,
                              hipStream_t stream) {
    const float* x     = (const float*)d_in[0];
    const int*   w     = (const int*)d_in[1];
    const float* bias  = (const float*)d_in[2];
    const float* p_sa  = (const float*)d_in[3];
    const int*   p_zpa = (const int*)d_in[4];
    const float* p_sw  = (const float*)d_in[5];
    const int*   p_wzp = (const int*)d_in[6];

    const int N = in_sizes[2];             // OUT
    const int K = in_sizes[1] / N;         // IN
    const int M = in_sizes[0] / K;         // B*S

    int8_t* xq = (int8_t*)d_ws;
    int8_t* wq = xq + (size_t)M * K;
    int* sum_x = (int*)(wq + (size_t)N * K);
    int* sum_w = sum_x + M;

    quant_x_kernel<<<M, 256, 0, stream>>>(x, xq, sum_x, p_sa, p_zpa, K);
    quant_w_kernel<<<N, 256, 0, stream>>>(w, wq, sum_w, K);

    const int nwg = (M / BM) * (N / BN);   // 1024
    gemm_i8_kernel<<<nwg, 512, 0, stream>>>(xq, wq, sum_x, sum_w, bias,
                                            (float*)d_out, p_sa, p_zpa, p_sw, p_wzp,
                                            M, N, K);
}

// Round 15
// 244.708 us; speedup vs baseline: 8.9251x; 1.0136x over previous
//
#include <hip/hip_runtime.h>
#include <stdint.h>

typedef int v4i  __attribute__((ext_vector_type(4)));
typedef int v16i __attribute__((ext_vector_type(16)));

// ---------------------------------------------------------------------------
// Kernel 1: quantize activations fp32 -> int8, plus per-row sums.
// ---------------------------------------------------------------------------
__global__ void quant_x_kernel(const float* __restrict__ x,
                               int8_t* __restrict__ xq,
                               int* __restrict__ sum_x,
                               const float* __restrict__ p_scale,
                               const int* __restrict__ p_zp,
                               int K) {
    const int row = blockIdx.x;
    const int t = threadIdx.x;
    const float s = p_scale[0];
    const float zpf = (float)p_zp[0];
    const float* xr = x + (size_t)row * K;
    int8_t* qr = xq + (size_t)row * K;
    int lsum = 0;
    const int nchunk = K >> 10;
    for (int i = 0; i < nchunk; ++i) {
        const int idx = (i << 10) + (t << 2);
        const float4 v = *reinterpret_cast<const float4*>(xr + idx);
        const float f0 = fminf(fmaxf(rintf(v.x / s) + zpf, -128.f), 127.f);
        const float f1 = fminf(fmaxf(rintf(v.y / s) + zpf, -128.f), 127.f);
        const float f2 = fminf(fmaxf(rintf(v.z / s) + zpf, -128.f), 127.f);
        const float f3 = fminf(fmaxf(rintf(v.w / s) + zpf, -128.f), 127.f);
        const int i0 = (int)f0, i1 = (int)f1, i2 = (int)f2, i3 = (int)f3;
        lsum += i0 + i1 + i2 + i3;
        const unsigned pk = (unsigned)(i0 & 255) | ((unsigned)(i1 & 255) << 8) |
                            ((unsigned)(i2 & 255) << 16) | ((unsigned)(i3 & 255) << 24);
        *reinterpret_cast<unsigned*>(qr + idx) = pk;
    }
    __shared__ int wsum[4];
    #pragma unroll
    for (int off = 32; off > 0; off >>= 1) lsum += __shfl_down(lsum, off);
    if ((t & 63) == 0) wsum[t >> 6] = lsum;
    __syncthreads();
    if (t == 0) sum_x[row] = wsum[0] + wsum[1] + wsum[2] + wsum[3];
}

// ---------------------------------------------------------------------------
// Kernel 2: pack weight int32 (int8-valued) -> int8, plus per-row sums.
// ---------------------------------------------------------------------------
__global__ void quant_w_kernel(const int* __restrict__ w,
                               int8_t* __restrict__ wq,
                               int* __restrict__ sum_w,
                               int K) {
    const int row = blockIdx.x;
    const int t = threadIdx.x;
    const int* wr_ = w + (size_t)row * K;
    int8_t* qr = wq + (size_t)row * K;
    int lsum = 0;
    const int nchunk = K >> 10;
    for (int i = 0; i < nchunk; ++i) {
        const int idx = (i << 10) + (t << 2);
        const int4 v = *reinterpret_cast<const int4*>(wr_ + idx);
        lsum += v.x + v.y + v.z + v.w;
        const unsigned pk = (unsigned)(v.x & 255) | ((unsigned)(v.y & 255) << 8) |
                            ((unsigned)(v.z & 255) << 16) | ((unsigned)(v.w & 255) << 24);
        *reinterpret_cast<unsigned*>(qr + idx) = pk;
    }
    __shared__ int wsum[4];
    #pragma unroll
    for (int off = 32; off > 0; off >>= 1) lsum += __shfl_down(lsum, off);
    if ((t & 63) == 0) wsum[t >> 6] = lsum;
    __syncthreads();
    if (t == 0) sum_w[row] = wsum[0] + wsum[1] + wsum[2] + wsum[3];
}

// ---------------------------------------------------------------------------
// Kernel 3: int8 GEMM, 256x256, 8 waves (2x4) -- r4 layout with TWO K-TILES
// PER BARRIER SEGMENT (the untried cell: long MFMA segment x 2 waves/SIMD).
//
// All prior structures pin at 28.3 cyc/MFMA (floor 9.15): r4 (2-phase,
// 3 barriers/tile), r10 (long segment, 1 wave/SIMD), r11 (fine 4-phase,
// 0 conflicts), r14 (2 blocks/CU). Surviving hypothesis: a fixed per-tile
// latency+sync cost (~1400 cyc: ds_read latency chains, DMA wait, 8-wave
// barrier convergence) amortized over too few MFMAs. This kernel amortizes
// it over 32 MFMAs/wave: per segment = {stage 2 tiles (8 pure-DMA gload) ;
// 24 ds_read_b128 ; 32 MFMA ; vmcnt(0) ; barrier}. 32 barriers/block vs
// r4's 192. DMA issues at segment head, drains ~2500 cyc later.
//
// Slot safety (4 slots, 2-tile segments): segment s reads slots
// {2s&3,(2s+1)&3}, stages {(2s+2)&3,(2s+3)&3} = the other pair (disjoint).
// The staged pair is read in segment s+1, AFTER this segment's vmcnt(0)
// drain + barrier. Reads of a slot complete (lgkmcnt before MFMA use)
// before the end barrier; its overwrite happens in segment s+1. SAFE.
// Pure-DMA stream + vmcnt(0) only (r9-verified; no counted-N over mixed
// streams). launch_bounds(512,1): no register cap (r12 lesson).
//
// Layout/swizzle byte-identical to r4/r6 (verified): stored chunk' =
// chunk ^ f(row), f(row)=((row>>1)^(row>>3))&3; linear DMA dest,
// inverse-swizzled per-lane source. XCD swizzle bijective (nwg=512).
// ---------------------------------------------------------------------------
#define BM 256
#define BN 256
#define BKB 64
#define NSLOT 4

__device__ __forceinline__ void gload_lds16(const void* g, void* l) {
    __builtin_amdgcn_global_load_lds(
        (const __attribute__((address_space(1))) unsigned int*)g,
        (__attribute__((address_space(3))) unsigned int*)l, 16, 0, 0);
}

#define MFMA_I8 __builtin_amdgcn_mfma_i32_32x32x32_i8

__global__ __launch_bounds__(512, 1)
void gemm_i8_kernel(const int8_t* __restrict__ xq,
                    const int8_t* __restrict__ wq,
                    const int* __restrict__ sum_x,
                    const int* __restrict__ sum_w,
                    const float* __restrict__ bias,
                    float* __restrict__ out,
                    const float* __restrict__ p_sa,
                    const int* __restrict__ p_zpa,
                    const float* __restrict__ p_sw,
                    const int* __restrict__ p_wzp,
                    int M, int N, int K) {
    __shared__ v4i ldsA[NSLOT][1024];   // 4 slots * 16KB = 64 KiB
    __shared__ v4i ldsB[NSLOT][1024];   // 128 KiB total

    const int tid = threadIdx.x;
    const int lane = tid & 63;
    const int wid = tid >> 6;
    const int wr = wid >> 2;            // 0..1: rows wr*128..+127
    const int wc = wid & 3;             // 0..3: cols wc*64..+63

    // XCD-aware bijective swizzle (nwg = 512, %8 == 0)
    const int nwgy = M / BM;
    const int nwg = nwgy * (N / BN);
    const int bid = blockIdx.x;
    const int v = (bid & 7) * (nwg >> 3) + (bid >> 3);
    const int m0 = (v % nwgy) * BM;
    const int n0 = (v / nwgy) * BN;

    // ---- staging (r6-verified): thread tid fills LDS chunk p = i*512 + tid.
    // row = i*128 + (tid>>2), stored chunk' = tid&3; source logical chunk =
    // chunk' ^ f(row), f(row) = ((row>>1)^(row>>3))&3.
    const int srow = tid >> 2;                          // 0..127
    const int schunk = (tid & 3) ^ (((srow >> 1) ^ (srow >> 3)) & 3);
    const int8_t* aS = xq + (size_t)(m0 + srow) * K + schunk * 16;
    const int8_t* bS = wq + (size_t)(n0 + srow) * K + schunk * 16;
    const size_t half = (size_t)128 * K;                // +128 rows
    const int dbase = wid * 64;                         // wave-uniform

    // ---- fragment reads (swizzled as stored)
    const int sel = ((lane >> 1) ^ (lane >> 3)) & 3;
    const int hi = lane >> 5;
    const int abase = (wr * 128 + (lane & 31)) * 4;
    const int bbase = (wc * 64 + (lane & 31)) * 4;
    const int c0 = hi ^ sel;            // ks0 stored chunk
    const int c1 = (2 + hi) ^ sel;      // ks1 stored chunk

    v16i acc[4][2] = {};
    const int NT = K / BKB;             // 64 (even)

#define STAGE_TILE(TT) do {                                                   \
        const int ns_ = (TT) & 3;                                             \
        const int8_t* pa_ = aS + (size_t)(TT) * BKB;                          \
        const int8_t* pb_ = bS + (size_t)(TT) * BKB;                          \
        gload_lds16(pa_,        &ldsA[ns_][dbase]);                           \
        gload_lds16(pa_ + half, &ldsA[ns_][dbase + 512]);                     \
        gload_lds16(pb_,        &ldsB[ns_][dbase]);                           \
        gload_lds16(pb_ + half, &ldsB[ns_][dbase + 512]);                     \
    } while (0)

    // ---- prologue: stage tiles 0,1; drain; publish.
    STAGE_TILE(0);
    STAGE_TILE(1);
    asm volatile("s_waitcnt vmcnt(0)" ::: "memory");
    __builtin_amdgcn_sched_barrier(0);
    __builtin_amdgcn_s_barrier();

    // ---- main loop: segments of 2 K-tiles, ONE barrier + ONE drain each.
    const int NSEG = NT / 2;            // 32
    for (int s = 0; s < NSEG; ++s) {
        const int t0 = 2 * s;
        // stage the NEXT segment's pair first (max latency headroom)
        if (s + 1 < NSEG) {
            STAGE_TILE(t0 + 2);
            STAGE_TILE(t0 + 3);
        }
        // read both tiles' fragments (compiler inserts fine-grained lgkmcnt)
        v4i a[2][8], b[2][4];
        #pragma unroll
        for (int j = 0; j < 2; ++j) {
            const v4i* LA = ldsA[(t0 + j) & 3];
            const v4i* LB = ldsB[(t0 + j) & 3];
            b[j][0] = LB[bbase + c0];
            b[j][1] = LB[bbase + c1];
            b[j][2] = LB[bbase + 128 + c0];
            b[j][3] = LB[bbase + 128 + c1];
            #pragma unroll
            for (int rf = 0; rf < 4; ++rf) {
                a[j][rf * 2 + 0] = LA[abase + rf * 128 + c0];
                a[j][rf * 2 + 1] = LA[abase + rf * 128 + c1];
            }
        }
        // 32 MFMAs back-to-back (longest uninterrupted matrix-pipe run)
        __builtin_amdgcn_s_setprio(1);
        #pragma unroll
        for (int j = 0; j < 2; ++j) {
            #pragma unroll
            for (int rf = 0; rf < 4; ++rf) {
                acc[rf][0] = MFMA_I8(a[j][rf * 2 + 0], b[j][0], acc[rf][0], 0, 0, 0);
                acc[rf][1] = MFMA_I8(a[j][rf * 2 + 0], b[j][2], acc[rf][1], 0, 0, 0);
                acc[rf][0] = MFMA_I8(a[j][rf * 2 + 1], b[j][1], acc[rf][0], 0, 0, 0);
                acc[rf][1] = MFMA_I8(a[j][rf * 2 + 1], b[j][3], acc[rf][1], 0, 0, 0);
            }
        }
        __builtin_amdgcn_s_setprio(0);
        // drain this segment's staging, publish to all waves.
        asm volatile("s_waitcnt vmcnt(0)" ::: "memory");
        __builtin_amdgcn_sched_barrier(0);
        __builtin_amdgcn_s_barrier();
    }
#undef STAGE_TILE

    // ---- epilogue: y = (acc - wzp*sum_x[m] - zp*sum_w[n] + K*zp*wzp)*(sa*sw) + bias[n]
    const float stot = p_sa[0] * p_sw[0];
    const int zpa = p_zpa[0];
    const int wzp = p_wzp[0];
    const int kzz = K * zpa * wzp;
    const int coll = lane & 31;
    const int rhi = (lane >> 5) * 4;

    #pragma unroll
    for (int cf = 0; cf < 2; ++cf) {
        const int cg = n0 + wc * 64 + cf * 32 + coll;
        const int sw = sum_w[cg];
        const float bb = bias[cg];
        #pragma unroll
        for (int rf = 0; rf < 4; ++rf) {
            const int rbase = m0 + wr * 128 + rf * 32 + rhi;
            #pragma unroll
            for (int r = 0; r < 16; ++r) {
                const int rowg = rbase + (r & 3) + 8 * (r >> 2);
                const int iv = acc[rf][cf][r] - wzp * sum_x[rowg] - zpa * sw + kzz;
                out[(size_t)rowg * N + cg] = (float)iv * stot + bb;
            }
        }
    }
}

// ---------------------------------------------------------------------------
extern "C" void kernel_launch(void* const* d_in, const int* in_sizes, int n_in,
                              void* d_out, int out_size, void* d_ws, size_t ws_size,
                              hipStream_t stream) {
    const float* x     = (const float*)d_in[0];
    const int*   w     = (const int*)d_in[1];
    const float* bias  = (const float*)d_in[2];
    const float* p_sa  = (const float*)d_in[3];
    const int*   p_zpa = (const int*)d_in[4];
    const float* p_sw  = (const float*)d_in[5];
    const int*   p_wzp = (const int*)d_in[6];

    const int N = in_sizes[2];             // OUT
    const int K = in_sizes[1] / N;         // IN
    const int M = in_sizes[0] / K;         // B*S

    int8_t* xq = (int8_t*)d_ws;
    int8_t* wq = xq + (size_t)M * K;
    int* sum_x = (int*)(wq + (size_t)N * K);
    int* sum_w = sum_x + M;

    quant_x_kernel<<<M, 256, 0, stream>>>(x, xq, sum_x, p_sa, p_zpa, K);
    quant_w_kernel<<<N, 256, 0, stream>>>(w, wq, sum_w, K);

    const int nwg = (M / BM) * (N / BN);   // 512
    gemm_i8_kernel<<<nwg, 512, 0, stream>>>(xq, wq, sum_x, sum_w, bias,
                                            (float*)d_out, p_sa, p_zpa, p_sw, p_wzp,
                                            M, N, K);
}